// Round 4
// baseline (177.793 us; speedup 1.0000x reference)
//
#include <hip/hip_runtime.h>

#define I_TOTAL 100000
#define DIM 64
#define BS 256

typedef __attribute__((ext_vector_type(8))) short bf16x8;
typedef __attribute__((ext_vector_type(4))) float f32x4;

__device__ inline unsigned short f2bf(float x) {
    union { float f; unsigned u; } v; v.f = x;
    return (unsigned short)((v.u + 0x8000u) >> 16);   // round-half-up to bf16
}

// Packed fp32->bf16 (RNE). No builtin on gfx950 -> inline asm.
__device__ inline unsigned pk_bf16(float lo, float hi) {
    unsigned r;
    asm("v_cvt_pk_bf16_f32 %0, %1, %2" : "=v"(r) : "v"(lo), "v"(hi));
    return r;
}

__device__ inline bf16x8 pack8(float4 a, float4 b) {
    union { unsigned u[4]; bf16x8 v; } r;
    r.u[0] = pk_bf16(a.x, a.y);
    r.u[1] = pk_bf16(a.z, a.w);
    r.u[2] = pk_bf16(b.x, b.y);
    r.u[3] = pk_bf16(b.z, b.w);
    return r.v;
}

// uniform-value float -> SGPR
__device__ inline float rfl(float x) {
    union { float f; int i; } u; u.f = x;
    u.i = __builtin_amdgcn_readfirstlane(u.i);
    return u.f;
}

// Convert item table fp32 -> bf16 once (BW-bound, ~6.5 us).
__global__ __launch_bounds__(256) void conv_items(
    const float* __restrict__ item, unsigned short* __restrict__ itbf)
{
    long t = (long)blockIdx.x * 256 + threadIdx.x;   // 0..799999
    const float4* p = (const float4*)(item + t * 8);
    float4 a = p[0], b = p[1];
    ushort4 r0, r1;
    r0.x = f2bf(a.x); r0.y = f2bf(a.y); r0.z = f2bf(a.z); r0.w = f2bf(a.w);
    r1.x = f2bf(b.x); r1.y = f2bf(b.y); r1.z = f2bf(b.z); r1.w = f2bf(b.w);
    ushort4* q = (ushort4*)(itbf + t * 8);
    q[0] = r0; q[1] = r1;
}

// 10 MFMAs of one 16b x 16i tile (K=64), zero C (bias folded into sw/swv).
__device__ inline void mfma_tile(const bf16x8 (&afr)[5][2], bf16x8 b0, bf16x8 b1,
                                 f32x4 (&acc)[5])
{
    const f32x4 zero = (f32x4){0.f, 0.f, 0.f, 0.f};
#pragma unroll
    for (int c = 0; c < 5; ++c) {
        acc[c] = __builtin_amdgcn_mfma_f32_16x16x32_bf16(afr[c][0], b0, zero, 0, 0, 0);
        acc[c] = __builtin_amdgcn_mfma_f32_16x16x32_bf16(afr[c][1], b1, acc[c], 0, 0, 0);
    }
}

// softmax-EV of one tile's acc -> LDS slot ti.
// prob_c = sw_c*e_c / sum(sw_c*e_c), e_c = exp2(acc_c), sw_c = exp2(bias_c*log2e)
__device__ inline void softmax_store(const f32x4 (&acc)[5], const float (&sw)[5],
                                     const float (&swv)[5], float* wlds, int ti)
{
#pragma unroll
    for (int rr = 0; rr < 4; ++rr) {
        float e0 = __builtin_amdgcn_exp2f(acc[0][rr]);
        float e1 = __builtin_amdgcn_exp2f(acc[1][rr]);
        float e2 = __builtin_amdgcn_exp2f(acc[2][rr]);
        float e3 = __builtin_amdgcn_exp2f(acc[3][rr]);
        float e4 = __builtin_amdgcn_exp2f(acc[4][rr]);
        float den = e0 * sw[0];
        den = fmaf(e1, sw[1], den);
        den = fmaf(e2, sw[2], den);
        den = fmaf(e3, sw[3], den);
        den = fmaf(e4, sw[4], den);
        float num = e0 * swv[0];
        num = fmaf(e1, swv[1], num);
        num = fmaf(e2, swv[2], num);
        num = fmaf(e3, swv[3], num);
        num = fmaf(e4, swv[4], num);
        wlds[rr * 64 + ti * 16] = num * __builtin_amdgcn_rcpf(den);
    }
}

// Main kernel: bf16 item loads, in-register A-prep, and a T15-style
// accA/accB pipeline: softmax of tile t-1 runs on the VALU while tile t's
// MFMAs are in the matrix pipe. LDS slots/readback unchanged.
// 1D grid of 1664 blocks (96 idle); blk%8 keyed to i-range -> per-XCD L2 reuse.
// Block: 16 b x 1024 i. Wave: 16 b x 256 i (16 tiles), 5 classes.
__global__ __launch_bounds__(256) void gemm_softmax(
    const unsigned short* __restrict__ itbf,
    const int* __restrict__ bu, const float* __restrict__ ut,
    const float* __restrict__ cw, const float* __restrict__ clsb,
    const float* __restrict__ vals, float* __restrict__ out)
{
    // per-wave private transpose buffer: 4 waves * 1056 dw = 16896 B.
    // slot(dw) = wave*1056 + quad*264 + rr*64 + ti*16 + col   (264 = 8-dw skew
    // per quad -> all LDS writes <=2-way bank aliased = free)
    __shared__ float ldsb[4224];

    const int blk = blockIdx.x;
    const int r8 = blk & 7;
    const int qq = blk >> 3;
    const int g  = qq & 15;          // b-group (16 b each)
    const int a  = qq >> 4;          // 0..12
    const int y  = a * 8 + r8;       // i-range id, 0..103
    if (y >= 98) return;

    const int lane = threadIdx.x & 63;
    const int wave = threadIdx.x >> 6;
    const int col  = lane & 15;     // A m-row (b in group) / C col (i in tile)
    const int quad = lane >> 4;

    const int b_base = g * 16;
    const int i_base = y * 1024 + wave * 256;   // this wave's 16 i-tiles

    const float s = 1.4426950408889634f;        // log2(e)

    // ---- A-prep in-register: M = u * W * log2e (bf16 fragments) ----
    const float* up = ut + (size_t)bu[b_base + col] * DIM + quad * 8;
    float4 u0 = *(const float4*)(up);
    float4 u1 = *(const float4*)(up + 4);
    float4 u2 = *(const float4*)(up + 32);
    float4 u3 = *(const float4*)(up + 36);
    u0.x *= s; u0.y *= s; u0.z *= s; u0.w *= s;
    u1.x *= s; u1.y *= s; u1.z *= s; u1.w *= s;
    u2.x *= s; u2.y *= s; u2.z *= s; u2.w *= s;
    u3.x *= s; u3.y *= s; u3.z *= s; u3.w *= s;

    bf16x8 afr[5][2];
    float sw[5], swv[5];
#pragma unroll
    for (int c = 0; c < 5; ++c) {
        const float* wp = cw + c * DIM + quad * 8;
        float4 w0 = *(const float4*)(wp);
        float4 w1 = *(const float4*)(wp + 4);
        float4 w2 = *(const float4*)(wp + 32);
        float4 w3 = *(const float4*)(wp + 36);
        float4 m0 = make_float4(u0.x*w0.x, u0.y*w0.y, u0.z*w0.z, u0.w*w0.w);
        float4 m1 = make_float4(u1.x*w1.x, u1.y*w1.y, u1.z*w1.z, u1.w*w1.w);
        float4 m2 = make_float4(u2.x*w2.x, u2.y*w2.y, u2.z*w2.z, u2.w*w2.w);
        float4 m3 = make_float4(u3.x*w3.x, u3.y*w3.y, u3.z*w3.z, u3.w*w3.w);
        afr[c][0] = pack8(m0, m1);
        afr[c][1] = pack8(m2, m3);
        float w = __builtin_amdgcn_exp2f(clsb[c] * s);   // exp2(bias*log2e)
        sw[c]  = rfl(w);
        swv[c] = rfl(w * vals[c]);
    }

    if (y < 97) {
        // ---- fast path ----
        float* wlds = ldsb + wave * 1056 + quad * 264 + col;           // write base
        const float* rlds = ldsb + wave * 1056 + quad * 264 + 4 * col; // read base

        float* op[4];
#pragma unroll
        for (int k = 0; k < 4; ++k)
            op[k] = out + (size_t)(b_base + quad * 4 + k) * I_TOTAL + (i_base + 4 * col);

        const unsigned short* bp = itbf + (size_t)(i_base + col) * DIM + quad * 8;

        // Prefetch tile 0. Deepest prefetch is tile index 16 -> row
        // i_base + 256 + col <= 99343 < 100000: always in bounds.
        bf16x8 pf0 = *(const bf16x8*)(bp);
        bf16x8 pf1 = *(const bf16x8*)(bp + 32);

        f32x4 accA[5], accB[5];

#pragma unroll 1
        for (int t4 = 0; t4 < 4; ++t4) {
            const unsigned short* base = bp + (size_t)(t4 * 4) * 1024;
            bf16x8 b0, b1;

            // t=0: MFMA->accA, load t+1
            b0 = pf0; b1 = pf1;
            pf0 = *(const bf16x8*)(base + 1024);
            pf1 = *(const bf16x8*)(base + 1024 + 32);
            mfma_tile(afr, b0, b1, accA);

            // t=1: MFMA->accB, load t+2, softmax(accA)
            b0 = pf0; b1 = pf1;
            pf0 = *(const bf16x8*)(base + 2048);
            pf1 = *(const bf16x8*)(base + 2048 + 32);
            mfma_tile(afr, b0, b1, accB);
            softmax_store(accA, sw, swv, wlds, 0);

            // t=2: MFMA->accA, load t+3, softmax(accB)
            b0 = pf0; b1 = pf1;
            pf0 = *(const bf16x8*)(base + 3072);
            pf1 = *(const bf16x8*)(base + 3072 + 32);
            mfma_tile(afr, b0, b1, accA);
            softmax_store(accB, sw, swv, wlds, 1);

            // t=3: MFMA->accB, load next group's t=0, softmax(accA)
            b0 = pf0; b1 = pf1;
            pf0 = *(const bf16x8*)(base + 4096);
            pf1 = *(const bf16x8*)(base + 4096 + 32);
            mfma_tile(afr, b0, b1, accB);
            softmax_store(accA, sw, swv, wlds, 2);

            // drain
            softmax_store(accB, sw, swv, wlds, 3);

            // transpose read-back: round k = b-row within quad; 1-KB wave stores
#pragma unroll
            for (int k = 0; k < 4; ++k) {
                f32x4 o4 = *(const f32x4*)(rlds + k * 64);
                *(f32x4*)op[k] = o4;
                op[k] += 64;
            }
        }
    } else {
        // ---- tail path (y == 97): clamp loads, guard stores ----
        float vv[5];
#pragma unroll
        for (int c = 0; c < 5; ++c) vv[c] = vals[c];
#pragma unroll 1
        for (int t = 0; t < 16; ++t) {
            int i  = i_base + t * 16 + col;
            int ic = i < I_TOTAL ? i : I_TOTAL - 1;
            const unsigned short* p2 = itbf + (size_t)ic * DIM + quad * 8;
            bf16x8 b0 = *(const bf16x8*)p2;
            bf16x8 b1 = *(const bf16x8*)(p2 + 32);
            f32x4 acc[5];
            mfma_tile(afr, b0, b1, acc);
            if (i < I_TOTAL) {
#pragma unroll
                for (int rr = 0; rr < 4; ++rr) {
                    // sw_c*e_c == exp2(acc + bias*log2e): same math as fast path
                    float e0 = __builtin_amdgcn_exp2f(acc[0][rr]);
                    float e1 = __builtin_amdgcn_exp2f(acc[1][rr]);
                    float e2 = __builtin_amdgcn_exp2f(acc[2][rr]);
                    float e3 = __builtin_amdgcn_exp2f(acc[3][rr]);
                    float e4 = __builtin_amdgcn_exp2f(acc[4][rr]);
                    float den = e0 * sw[0];
                    den = fmaf(e1, sw[1], den);
                    den = fmaf(e2, sw[2], den);
                    den = fmaf(e3, sw[3], den);
                    den = fmaf(e4, sw[4], den);
                    float num = e0 * swv[0];
                    num = fmaf(e1, swv[1], num);
                    num = fmaf(e2, swv[2], num);
                    num = fmaf(e3, swv[3], num);
                    num = fmaf(e4, swv[4], num);
                    out[(size_t)(b_base + quad * 4 + rr) * I_TOTAL + i] =
                        num * __builtin_amdgcn_rcpf(den);
                }
            }
        }
        (void)vv;
    }
}

// Fallback (no workspace): R1's fused fp32-load kernel (passed, 94.9 us).
__global__ __launch_bounds__(256) void gemm_softmax_fb(
    const int* __restrict__ bu, const float* __restrict__ ut,
    const float* __restrict__ it, const float* __restrict__ cw,
    const float* __restrict__ clsb, const float* __restrict__ vals,
    float* __restrict__ out)
{
    __shared__ float ldsb[4224];

    const int blk = blockIdx.x;
    const int r8 = blk & 7;
    const int qq = blk >> 3;
    const int g  = qq & 15;
    const int a  = qq >> 4;
    const int y  = a * 8 + r8;
    if (y >= 98) return;

    const int lane = threadIdx.x & 63;
    const int wave = threadIdx.x >> 6;
    const int col  = lane & 15;
    const int quad = lane >> 4;

    const int b_base = g * 16;
    const int i_base = y * 1024 + wave * 256;

    const float s = 1.4426950408889634f;

    const float* up = ut + (size_t)bu[b_base + col] * DIM + quad * 8;
    float4 u0 = *(const float4*)(up);
    float4 u1 = *(const float4*)(up + 4);
    float4 u2 = *(const float4*)(up + 32);
    float4 u3 = *(const float4*)(up + 36);
    u0.x *= s; u0.y *= s; u0.z *= s; u0.w *= s;
    u1.x *= s; u1.y *= s; u1.z *= s; u1.w *= s;
    u2.x *= s; u2.y *= s; u2.z *= s; u2.w *= s;
    u3.x *= s; u3.y *= s; u3.z *= s; u3.w *= s;

    bf16x8 afr[5][2];
    f32x4 cin[5];
    float vv[5];
#pragma unroll
    for (int c = 0; c < 5; ++c) {
        const float* wp = cw + c * DIM + quad * 8;
        float4 w0 = *(const float4*)(wp);
        float4 w1 = *(const float4*)(wp + 4);
        float4 w2 = *(const float4*)(wp + 32);
        float4 w3 = *(const float4*)(wp + 36);
        float4 m0 = make_float4(u0.x*w0.x, u0.y*w0.y, u0.z*w0.z, u0.w*w0.w);
        float4 m1 = make_float4(u1.x*w1.x, u1.y*w1.y, u1.z*w1.z, u1.w*w1.w);
        float4 m2 = make_float4(u2.x*w2.x, u2.y*w2.y, u2.z*w2.z, u2.w*w2.w);
        float4 m3 = make_float4(u3.x*w3.x, u3.y*w3.y, u3.z*w3.z, u3.w*w3.w);
        afr[c][0] = pack8(m0, m1);
        afr[c][1] = pack8(m2, m3);
        float bc = clsb[c] * s;
        cin[c] = (f32x4){bc, bc, bc, bc};
        vv[c] = vals[c];
    }

    if (y < 97) {
        float* wlds = ldsb + wave * 1056 + quad * 264 + col;
        const float* rlds = ldsb + wave * 1056 + quad * 264 + 4 * col;

        float* op[4];
#pragma unroll
        for (int k = 0; k < 4; ++k)
            op[k] = out + (size_t)(b_base + quad * 4 + k) * I_TOTAL + (i_base + 4 * col);

        const float* bp = it + (size_t)(i_base + col) * DIM + quad * 8;

#pragma unroll 1
        for (int t4 = 0; t4 < 4; ++t4) {
#pragma unroll
            for (int ti = 0; ti < 4; ++ti) {
                const float* p = bp + ti * 1024;
                float4 q0 = *(const float4*)(p);
                float4 q1 = *(const float4*)(p + 4);
                float4 q2 = *(const float4*)(p + 32);
                float4 q3 = *(const float4*)(p + 36);
                bf16x8 b0 = pack8(q0, q1);
                bf16x8 b1 = pack8(q2, q3);
                f32x4 acc[5];
#pragma unroll
                for (int c = 0; c < 5; ++c) {
                    acc[c] = __builtin_amdgcn_mfma_f32_16x16x32_bf16(afr[c][0], b0, cin[c], 0, 0, 0);
                    acc[c] = __builtin_amdgcn_mfma_f32_16x16x32_bf16(afr[c][1], b1, acc[c], 0, 0, 0);
                }
#pragma unroll
                for (int rr = 0; rr < 4; ++rr) {
                    float e0 = __builtin_amdgcn_exp2f(acc[0][rr]);
                    float e1 = __builtin_amdgcn_exp2f(acc[1][rr]);
                    float e2 = __builtin_amdgcn_exp2f(acc[2][rr]);
                    float e3 = __builtin_amdgcn_exp2f(acc[3][rr]);
                    float e4 = __builtin_amdgcn_exp2f(acc[4][rr]);
                    float den = ((e0 + e1) + (e2 + e3)) + e4;
                    float num = e0 * vv[0];
                    num = fmaf(e1, vv[1], num);
                    num = fmaf(e2, vv[2], num);
                    num = fmaf(e3, vv[3], num);
                    num = fmaf(e4, vv[4], num);
                    wlds[rr * 64 + ti * 16] = num * __builtin_amdgcn_rcpf(den);
                }
            }
#pragma unroll
            for (int k = 0; k < 4; ++k) {
                f32x4 o4 = *(const f32x4*)(rlds + k * 64);
                *(f32x4*)op[k] = o4;
                op[k] += 64;
            }
            bp += 4 * 1024;
        }
    } else {
#pragma unroll 1
        for (int t = 0; t < 16; ++t) {
            int i  = i_base + t * 16 + col;
            int ic = i < I_TOTAL ? i : I_TOTAL - 1;
            const float* p2 = it + (size_t)ic * DIM + quad * 8;
            float4 q0 = *(const float4*)(p2);
            float4 q1 = *(const float4*)(p2 + 4);
            float4 q2 = *(const float4*)(p2 + 32);
            float4 q3 = *(const float4*)(p2 + 36);
            bf16x8 b0 = pack8(q0, q1);
            bf16x8 b1 = pack8(q2, q3);
            f32x4 acc[5];
#pragma unroll
            for (int c = 0; c < 5; ++c) {
                acc[c] = __builtin_amdgcn_mfma_f32_16x16x32_bf16(afr[c][0], b0, cin[c], 0, 0, 0);
                acc[c] = __builtin_amdgcn_mfma_f32_16x16x32_bf16(afr[c][1], b1, acc[c], 0, 0, 0);
            }
            if (i < I_TOTAL) {
#pragma unroll
                for (int rr = 0; rr < 4; ++rr) {
                    float e0 = __builtin_amdgcn_exp2f(acc[0][rr]);
                    float e1 = __builtin_amdgcn_exp2f(acc[1][rr]);
                    float e2 = __builtin_amdgcn_exp2f(acc[2][rr]);
                    float e3 = __builtin_amdgcn_exp2f(acc[3][rr]);
                    float e4 = __builtin_amdgcn_exp2f(acc[4][rr]);
                    float den = ((e0 + e1) + (e2 + e3)) + e4;
                    float num = e0 * vv[0];
                    num = fmaf(e1, vv[1], num);
                    num = fmaf(e2, vv[2], num);
                    num = fmaf(e3, vv[3], num);
                    num = fmaf(e4, vv[4], num);
                    out[(size_t)(b_base + quad * 4 + rr) * I_TOTAL + i] =
                        num * __builtin_amdgcn_rcpf(den);
                }
            }
        }
    }
}

extern "C" void kernel_launch(void* const* d_in, const int* in_sizes, int n_in,
                              void* d_out, int out_size, void* d_ws, size_t ws_size,
                              hipStream_t stream) {
    const int*   bu   = (const int*)d_in[0];
    const float* ut   = (const float*)d_in[1];
    const float* it   = (const float*)d_in[2];
    const float* cw   = (const float*)d_in[3];
    const float* cb   = (const float*)d_in[4];
    const float* vals = (const float*)d_in[5];
    float* out = (float*)d_out;
    unsigned short* itbf = (unsigned short*)d_ws;    // 12.8 MB

    const size_t needed = (size_t)I_TOTAL * DIM * 2;

    if (ws_size >= needed) {
        conv_items<<<3125, 256, 0, stream>>>(it, itbf);
        gemm_softmax<<<1664, 256, 0, stream>>>(itbf, bu, ut, cw, cb, vals, out);
    } else {
        gemm_softmax_fb<<<1664, 256, 0, stream>>>(bu, ut, it, cw, cb, vals, out);
    }
}

// Round 5
// 174.625 us; speedup vs baseline: 1.0181x; 1.0181x over previous
//
#include <hip/hip_runtime.h>

#define I_TOTAL 100000
#define DIM 64
#define BS 256

typedef __attribute__((ext_vector_type(8))) short bf16x8;
typedef __attribute__((ext_vector_type(4))) float f32x4;

__device__ inline unsigned short f2bf(float x) {
    union { float f; unsigned u; } v; v.f = x;
    return (unsigned short)((v.u + 0x8000u) >> 16);   // round-half-up to bf16
}

// Packed fp32->bf16 (RNE). No builtin on gfx950 -> inline asm.
__device__ inline unsigned pk_bf16(float lo, float hi) {
    unsigned r;
    asm("v_cvt_pk_bf16_f32 %0, %1, %2" : "=v"(r) : "v"(lo), "v"(hi));
    return r;
}

__device__ inline bf16x8 pack8(float4 a, float4 b) {
    union { unsigned u[4]; bf16x8 v; } r;
    r.u[0] = pk_bf16(a.x, a.y);
    r.u[1] = pk_bf16(a.z, a.w);
    r.u[2] = pk_bf16(b.x, b.y);
    r.u[3] = pk_bf16(b.z, b.w);
    return r.v;
}

// uniform-value float -> SGPR
__device__ inline float rfl(float x) {
    union { float f; int i; } u; u.f = x;
    u.i = __builtin_amdgcn_readfirstlane(u.i);
    return u.f;
}

// Convert item table fp32 -> bf16 once (BW-bound, ~6.5 us).
__global__ __launch_bounds__(256) void conv_items(
    const float* __restrict__ item, unsigned short* __restrict__ itbf)
{
    long t = (long)blockIdx.x * 256 + threadIdx.x;   // 0..799999
    const float4* p = (const float4*)(item + t * 8);
    float4 a = p[0], b = p[1];
    ushort4 r0, r1;
    r0.x = f2bf(a.x); r0.y = f2bf(a.y); r0.z = f2bf(a.z); r0.w = f2bf(a.w);
    r1.x = f2bf(b.x); r1.y = f2bf(b.y); r1.z = f2bf(b.z); r1.w = f2bf(b.w);
    ushort4* q = (ushort4*)(itbf + t * 8);
    q[0] = r0; q[1] = r1;
}

// 10 MFMAs of one 16b x 16i tile (K=64), zero C (bias folded into sw/swv).
__device__ inline void mfma_tile(const bf16x8 (&afr)[5][2], bf16x8 b0, bf16x8 b1,
                                 f32x4 (&acc)[5])
{
    const f32x4 zero = (f32x4){0.f, 0.f, 0.f, 0.f};
#pragma unroll
    for (int c = 0; c < 5; ++c) {
        acc[c] = __builtin_amdgcn_mfma_f32_16x16x32_bf16(afr[c][0], b0, zero, 0, 0, 0);
        acc[c] = __builtin_amdgcn_mfma_f32_16x16x32_bf16(afr[c][1], b1, acc[c], 0, 0, 0);
    }
}

// softmax-EV of one tile's acc -> LDS slot ti.
// prob_c = sw_c*e_c / sum(sw_c*e_c), e_c = exp2(acc_c), sw_c = exp2(bias_c*log2e)
__device__ inline void softmax_store(const f32x4 (&acc)[5], const float (&sw)[5],
                                     const float (&swv)[5], float* wlds, int ti)
{
#pragma unroll
    for (int rr = 0; rr < 4; ++rr) {
        float e0 = __builtin_amdgcn_exp2f(acc[0][rr]);
        float e1 = __builtin_amdgcn_exp2f(acc[1][rr]);
        float e2 = __builtin_amdgcn_exp2f(acc[2][rr]);
        float e3 = __builtin_amdgcn_exp2f(acc[3][rr]);
        float e4 = __builtin_amdgcn_exp2f(acc[4][rr]);
        float den = e0 * sw[0];
        den = fmaf(e1, sw[1], den);
        den = fmaf(e2, sw[2], den);
        den = fmaf(e3, sw[3], den);
        den = fmaf(e4, sw[4], den);
        float num = e0 * swv[0];
        num = fmaf(e1, swv[1], num);
        num = fmaf(e2, swv[2], num);
        num = fmaf(e3, swv[3], num);
        num = fmaf(e4, swv[4], num);
        wlds[rr * 64 + ti * 16] = num * __builtin_amdgcn_rcpf(den);
    }
}

// Main kernel, 1-wave workgroups (64 threads). No cross-wave cooperation
// exists (per-wave-private LDS, no barriers), so 4-wave gangs only hurt
// scheduling granularity: R1 profile showed 22.5% occupancy / no pipe >25%
// busy = TLP-starved. 6656 blocks = 104 y x 16 g x 4 i-sub (384 no-op);
// blk&7 keys y-set to XCD -> each XCD re-reads its ~1.7 MB L2 item slice.
// Wave: 16 b x 256 i (16 tiles), 5 classes.
__global__ __launch_bounds__(64) void gemm_softmax(
    const unsigned short* __restrict__ itbf,
    const int* __restrict__ bu, const float* __restrict__ ut,
    const float* __restrict__ cw, const float* __restrict__ clsb,
    const float* __restrict__ vals, float* __restrict__ out)
{
    // per-wave transpose buffer: 1056 dw = 4224 B.
    // slot(dw) = quad*264 + rr*64 + ti*16 + col   (264 = 8-dw skew per quad
    // -> all LDS ops <=2-way bank aliased = free)
    __shared__ float ldsb[1056];

    const int blk  = blockIdx.x;
    const int r8   = blk & 7;
    const int rest = blk >> 3;       // 0..831
    const int wv   = rest & 3;       // i-subrange within y (replaces wave id)
    const int qq   = rest >> 2;      // 0..207
    const int g    = qq & 15;        // b-group (16 b each)
    const int a    = qq >> 4;        // 0..12
    const int y    = a * 8 + r8;     // i-range id, 0..103
    if (y >= 98) return;

    const int lane = threadIdx.x & 63;
    const int col  = lane & 15;     // A m-row (b in group) / C col (i in tile)
    const int quad = lane >> 4;

    const int b_base = g * 16;
    const int i_base = y * 1024 + wv * 256;   // this wave's 16 i-tiles

    const float s = 1.4426950408889634f;        // log2(e)

    // ---- A-prep in-register: M = u * W * log2e (bf16 fragments) ----
    const float* up = ut + (size_t)bu[b_base + col] * DIM + quad * 8;
    float4 u0 = *(const float4*)(up);
    float4 u1 = *(const float4*)(up + 4);
    float4 u2 = *(const float4*)(up + 32);
    float4 u3 = *(const float4*)(up + 36);
    u0.x *= s; u0.y *= s; u0.z *= s; u0.w *= s;
    u1.x *= s; u1.y *= s; u1.z *= s; u1.w *= s;
    u2.x *= s; u2.y *= s; u2.z *= s; u2.w *= s;
    u3.x *= s; u3.y *= s; u3.z *= s; u3.w *= s;

    bf16x8 afr[5][2];
    float sw[5], swv[5];
#pragma unroll
    for (int c = 0; c < 5; ++c) {
        const float* wp = cw + c * DIM + quad * 8;
        float4 w0 = *(const float4*)(wp);
        float4 w1 = *(const float4*)(wp + 4);
        float4 w2 = *(const float4*)(wp + 32);
        float4 w3 = *(const float4*)(wp + 36);
        float4 m0 = make_float4(u0.x*w0.x, u0.y*w0.y, u0.z*w0.z, u0.w*w0.w);
        float4 m1 = make_float4(u1.x*w1.x, u1.y*w1.y, u1.z*w1.z, u1.w*w1.w);
        float4 m2 = make_float4(u2.x*w2.x, u2.y*w2.y, u2.z*w2.z, u2.w*w2.w);
        float4 m3 = make_float4(u3.x*w3.x, u3.y*w3.y, u3.z*w3.z, u3.w*w3.w);
        afr[c][0] = pack8(m0, m1);
        afr[c][1] = pack8(m2, m3);
        float w = __builtin_amdgcn_exp2f(clsb[c] * s);   // exp2(bias*log2e)
        sw[c]  = rfl(w);
        swv[c] = rfl(w * vals[c]);
    }

    if (y < 97) {
        // ---- fast path ----
        float* wlds = ldsb + quad * 264 + col;           // write base
        const float* rlds = ldsb + quad * 264 + 4 * col; // read base

        float* op[4];
#pragma unroll
        for (int k = 0; k < 4; ++k)
            op[k] = out + (size_t)(b_base + quad * 4 + k) * I_TOTAL + (i_base + 4 * col);

        const unsigned short* bp = itbf + (size_t)(i_base + col) * DIM + quad * 8;

#pragma unroll 1
        for (int t4 = 0; t4 < 4; ++t4) {
#pragma unroll
            for (int ti = 0; ti < 4; ++ti) {
                bf16x8 b0 = *(const bf16x8*)(bp + ti * 1024);
                bf16x8 b1 = *(const bf16x8*)(bp + ti * 1024 + 32);
                f32x4 acc[5];
                mfma_tile(afr, b0, b1, acc);
                softmax_store(acc, sw, swv, wlds, ti);
            }
            // transpose read-back: round k = b-row within quad; 1-KB wave stores
#pragma unroll
            for (int k = 0; k < 4; ++k) {
                f32x4 o4 = *(const f32x4*)(rlds + k * 64);
                *(f32x4*)op[k] = o4;
                op[k] += 64;
            }
            bp += 4 * 1024;
        }
    } else {
        // ---- tail path (y == 97): clamp loads, guard stores ----
#pragma unroll 1
        for (int t = 0; t < 16; ++t) {
            int i  = i_base + t * 16 + col;
            int ic = i < I_TOTAL ? i : I_TOTAL - 1;
            const unsigned short* p2 = itbf + (size_t)ic * DIM + quad * 8;
            bf16x8 b0 = *(const bf16x8*)p2;
            bf16x8 b1 = *(const bf16x8*)(p2 + 32);
            f32x4 acc[5];
            mfma_tile(afr, b0, b1, acc);
            if (i < I_TOTAL) {
#pragma unroll
                for (int rr = 0; rr < 4; ++rr) {
                    // sw_c*e_c == exp2(acc + bias*log2e): same math as fast path
                    float e0 = __builtin_amdgcn_exp2f(acc[0][rr]);
                    float e1 = __builtin_amdgcn_exp2f(acc[1][rr]);
                    float e2 = __builtin_amdgcn_exp2f(acc[2][rr]);
                    float e3 = __builtin_amdgcn_exp2f(acc[3][rr]);
                    float e4 = __builtin_amdgcn_exp2f(acc[4][rr]);
                    float den = e0 * sw[0];
                    den = fmaf(e1, sw[1], den);
                    den = fmaf(e2, sw[2], den);
                    den = fmaf(e3, sw[3], den);
                    den = fmaf(e4, sw[4], den);
                    float num = e0 * swv[0];
                    num = fmaf(e1, swv[1], num);
                    num = fmaf(e2, swv[2], num);
                    num = fmaf(e3, swv[3], num);
                    num = fmaf(e4, swv[4], num);
                    out[(size_t)(b_base + quad * 4 + rr) * I_TOTAL + i] =
                        num * __builtin_amdgcn_rcpf(den);
                }
            }
        }
    }
}

// Fallback (no workspace): fused fp32-load kernel (R1 structure, passed).
__global__ __launch_bounds__(256) void gemm_softmax_fb(
    const int* __restrict__ bu, const float* __restrict__ ut,
    const float* __restrict__ it, const float* __restrict__ cw,
    const float* __restrict__ clsb, const float* __restrict__ vals,
    float* __restrict__ out)
{
    __shared__ float ldsb[4224];

    const int blk = blockIdx.x;
    const int r8 = blk & 7;
    const int qq = blk >> 3;
    const int g  = qq & 15;
    const int a  = qq >> 4;
    const int y  = a * 8 + r8;
    if (y >= 98) return;

    const int lane = threadIdx.x & 63;
    const int wave = threadIdx.x >> 6;
    const int col  = lane & 15;
    const int quad = lane >> 4;

    const int b_base = g * 16;
    const int i_base = y * 1024 + wave * 256;

    const float s = 1.4426950408889634f;

    const float* up = ut + (size_t)bu[b_base + col] * DIM + quad * 8;
    float4 u0 = *(const float4*)(up);
    float4 u1 = *(const float4*)(up + 4);
    float4 u2 = *(const float4*)(up + 32);
    float4 u3 = *(const float4*)(up + 36);
    u0.x *= s; u0.y *= s; u0.z *= s; u0.w *= s;
    u1.x *= s; u1.y *= s; u1.z *= s; u1.w *= s;
    u2.x *= s; u2.y *= s; u2.z *= s; u2.w *= s;
    u3.x *= s; u3.y *= s; u3.z *= s; u3.w *= s;

    bf16x8 afr[5][2];
    float sw[5], swv[5];
#pragma unroll
    for (int c = 0; c < 5; ++c) {
        const float* wp = cw + c * DIM + quad * 8;
        float4 w0 = *(const float4*)(wp);
        float4 w1 = *(const float4*)(wp + 4);
        float4 w2 = *(const float4*)(wp + 32);
        float4 w3 = *(const float4*)(wp + 36);
        float4 m0 = make_float4(u0.x*w0.x, u0.y*w0.y, u0.z*w0.z, u0.w*w0.w);
        float4 m1 = make_float4(u1.x*w1.x, u1.y*w1.y, u1.z*w1.z, u1.w*w1.w);
        float4 m2 = make_float4(u2.x*w2.x, u2.y*w2.y, u2.z*w2.z, u2.w*w2.w);
        float4 m3 = make_float4(u3.x*w3.x, u3.y*w3.y, u3.z*w3.z, u3.w*w3.w);
        afr[c][0] = pack8(m0, m1);
        afr[c][1] = pack8(m2, m3);
        float w = __builtin_amdgcn_exp2f(clsb[c] * s);
        sw[c]  = rfl(w);
        swv[c] = rfl(w * vals[c]);
    }

    if (y < 97) {
        float* wlds = ldsb + wave * 1056 + quad * 264 + col;
        const float* rlds = ldsb + wave * 1056 + quad * 264 + 4 * col;

        float* op[4];
#pragma unroll
        for (int k = 0; k < 4; ++k)
            op[k] = out + (size_t)(b_base + quad * 4 + k) * I_TOTAL + (i_base + 4 * col);

        const float* bp = it + (size_t)(i_base + col) * DIM + quad * 8;

#pragma unroll 1
        for (int t4 = 0; t4 < 4; ++t4) {
#pragma unroll
            for (int ti = 0; ti < 4; ++ti) {
                const float* p = bp + ti * 1024;
                float4 q0 = *(const float4*)(p);
                float4 q1 = *(const float4*)(p + 4);
                float4 q2 = *(const float4*)(p + 32);
                float4 q3 = *(const float4*)(p + 36);
                bf16x8 b0 = pack8(q0, q1);
                bf16x8 b1 = pack8(q2, q3);
                f32x4 acc[5];
                mfma_tile(afr, b0, b1, acc);
                softmax_store(acc, sw, swv, wlds, ti);
            }
#pragma unroll
            for (int k = 0; k < 4; ++k) {
                f32x4 o4 = *(const f32x4*)(rlds + k * 64);
                *(f32x4*)op[k] = o4;
                op[k] += 64;
            }
            bp += 4 * 1024;
        }
    } else {
#pragma unroll 1
        for (int t = 0; t < 16; ++t) {
            int i  = i_base + t * 16 + col;
            int ic = i < I_TOTAL ? i : I_TOTAL - 1;
            const float* p2 = it + (size_t)ic * DIM + quad * 8;
            float4 q0 = *(const float4*)(p2);
            float4 q1 = *(const float4*)(p2 + 4);
            float4 q2 = *(const float4*)(p2 + 32);
            float4 q3 = *(const float4*)(p2 + 36);
            bf16x8 b0 = pack8(q0, q1);
            bf16x8 b1 = pack8(q2, q3);
            f32x4 acc[5];
            mfma_tile(afr, b0, b1, acc);
            if (i < I_TOTAL) {
#pragma unroll
                for (int rr = 0; rr < 4; ++rr) {
                    float e0 = __builtin_amdgcn_exp2f(acc[0][rr]);
                    float e1 = __builtin_amdgcn_exp2f(acc[1][rr]);
                    float e2 = __builtin_amdgcn_exp2f(acc[2][rr]);
                    float e3 = __builtin_amdgcn_exp2f(acc[3][rr]);
                    float e4 = __builtin_amdgcn_exp2f(acc[4][rr]);
                    float den = e0 * sw[0];
                    den = fmaf(e1, sw[1], den);
                    den = fmaf(e2, sw[2], den);
                    den = fmaf(e3, sw[3], den);
                    den = fmaf(e4, sw[4], den);
                    float num = e0 * swv[0];
                    num = fmaf(e1, swv[1], num);
                    num = fmaf(e2, swv[2], num);
                    num = fmaf(e3, swv[3], num);
                    num = fmaf(e4, swv[4], num);
                    out[(size_t)(b_base + quad * 4 + rr) * I_TOTAL + i] =
                        num * __builtin_amdgcn_rcpf(den);
                }
            }
        }
    }
}

extern "C" void kernel_launch(void* const* d_in, const int* in_sizes, int n_in,
                              void* d_out, int out_size, void* d_ws, size_t ws_size,
                              hipStream_t stream) {
    const int*   bu   = (const int*)d_in[0];
    const float* ut   = (const float*)d_in[1];
    const float* it   = (const float*)d_in[2];
    const float* cw   = (const float*)d_in[3];
    const float* cb   = (const float*)d_in[4];
    const float* vals = (const float*)d_in[5];
    float* out = (float*)d_out;
    unsigned short* itbf = (unsigned short*)d_ws;    // 12.8 MB

    const size_t needed = (size_t)I_TOTAL * DIM * 2;

    if (ws_size >= needed) {
        conv_items<<<3125, 256, 0, stream>>>(it, itbf);
        gemm_softmax<<<6656, 64, 0, stream>>>(itbf, bu, ut, cw, cb, vals, out);
    } else {
        gemm_softmax_fb<<<1664, 256, 0, stream>>>(bu, ut, it, cw, cb, vals, out);
    }
}